// Round 7
// baseline (625.207 us; speedup 1.0000x reference)
//
#include <hip/hip_runtime.h>

typedef unsigned short u16;
typedef short bf16x8 __attribute__((ext_vector_type(8)));
typedef float f32x4 __attribute__((ext_vector_type(4)));

#define NBATCH 8192

__device__ __forceinline__ f32x4 mfma16(bf16x8 a, bf16x8 b, f32x4 c) {
  return __builtin_amdgcn_mfma_f32_16x16x32_bf16(a, b, c, 0, 0, 0);
}
__device__ __forceinline__ u16 f2bf(float f) {
  unsigned int u = __float_as_uint(f);
  return (u16)((u + 0x7FFFu + ((u >> 16) & 1u)) >> 16);
}
__device__ __forceinline__ float bf2f(u16 h) {
  return __uint_as_float(((unsigned int)h) << 16);
}
__device__ __forceinline__ float sigm(float x) {
  return __builtin_amdgcn_rcpf(1.f + __builtin_amdgcn_exp2f(-1.44269504f * x));
}
__device__ __forceinline__ float tanh_(float x) {
  float t = __builtin_amdgcn_exp2f(2.88539008f * x);
  return 1.f - 2.f * __builtin_amdgcn_rcpf(t + 1.f);
}
__device__ __forceinline__ bf16x8 pack8(const float* p) {
  float4 a = *(const float4*)p, b = *(const float4*)(p + 4);
  bf16x8 r;
  r[0] = (short)f2bf(a.x); r[1] = (short)f2bf(a.y);
  r[2] = (short)f2bf(a.z); r[3] = (short)f2bf(a.w);
  r[4] = (short)f2bf(b.x); r[5] = (short)f2bf(b.y);
  r[6] = (short)f2bf(b.z); r[7] = (short)f2bf(b.w);
  return r;
}

// =====================================================================
// Wave-specialized fused GRU: one 1024-thread block = 8 L0-waves + 8
// L1-waves, L1 one step behind L0, h0 handed off in LDS. 65 iterations,
// ONE barrier each. R6 post-mortem: layer-split removed spills but
// doubled the serial chain (128 step-barriers) and pushed h0 through
// HBM. Here: no global h0, serial chain 65, and 16 waves/CU = 4
// waves/SIMD (vs 2 in R2-R6) to hide trans/LDS/barrier latency.
// Register trick: W_hh0 (L0 role) and W_ih1 (L1 role) live in the SAME
// 48-VGPR array loaded from a role-dependent pointer -> the two roles
// share physical registers and demand stays ~124 <= the 128 cap.
// W_hh1 stays in LDS (96K). Numerics identical to R3-R6 (same bf16
// rounding points).
// =====================================================================
#define W1_OFF 0
#define H0B_OFF 98304
#define H1B_OFF 114688
#define XB_OFF  131072
#define GRU_LDS 135168

// one pipeline iteration; P = parity literal, K = iteration index.
// L0 (waves 0-7) computes h0(K) if K<64; L1 (waves 8-15) computes h1(K-1) if K>=1.
#define FITER(P, K)                                                             \
  {                                                                             \
    if (xact && (K) < 63) {                                                     \
      u16 xh = f2bf(xv);                                                        \
      u16 xl = f2bf(xv - bf2f(xh));                                             \
      char* xw = sm + XB_OFF + ((P)^1)*2048 + xm*64 + xd*2;                     \
      *(u16*)xw = xh; *(u16*)(xw + 16) = xl; *(u16*)(xw + 32) = xh;             \
      if ((K) < 62) xv = gx[(K) + 2];                                           \
    }                                                                           \
    if (isL0 ? ((K) < 64) : ((K) >= 1)) {                                       \
      f32x4 rzr[2], rzz[2], cc[2], dd[2];                                       \
      _Pragma("unroll") for (int mt = 0; mt < 2; ++mt) {                        \
        rzr[mt] = (f32x4){brzr, brzr, brzr, brzr};                              \
        rzz[mt] = (f32x4){brzz, brzz, brzz, brzz};                              \
        cc[mt]  = (f32x4){bcc, bcc, bcc, bcc};                                  \
        dd[mt]  = (f32x4){bdd, bdd, bdd, bdd};                                  \
      }                                                                         \
      _Pragma("unroll") for (int ki = 0; ki < 4; ++ki) {                        \
        bf16x8 a0 = *(bf16x8*)(sm + H0B_OFF + ((P)^1)*8192 + arow0 + ad[ki]);   \
        bf16x8 a1 = *(bf16x8*)(sm + H0B_OFF + ((P)^1)*8192 + arow1 + ad[ki]);   \
        rzr[0] = mfma16(a0, wfrag[0][ki], rzr[0]);                              \
        rzr[1] = mfma16(a1, wfrag[0][ki], rzr[1]);                              \
        rzz[0] = mfma16(a0, wfrag[1][ki], rzz[0]);                              \
        rzz[1] = mfma16(a1, wfrag[1][ki], rzz[1]);                              \
        cc[0]  = mfma16(a0, wfrag[2][ki], cc[0]);                               \
        cc[1]  = mfma16(a1, wfrag[2][ki], cc[1]);                               \
      }                                                                         \
      if (isL0) {                                                               \
        bf16x8 ax0 = *(bf16x8*)(sm + XB_OFF + (P)*2048 + xr0);                  \
        bf16x8 ax1 = *(bf16x8*)(sm + XB_OFF + (P)*2048 + xr1);                  \
        rzr[0] = mfma16(ax0, wf0a, rzr[0]);                                     \
        rzr[1] = mfma16(ax1, wf0a, rzr[1]);                                     \
        rzz[0] = mfma16(ax0, wf0b, rzz[0]);                                     \
        rzz[1] = mfma16(ax1, wf0b, rzz[1]);                                     \
        dd[0]  = mfma16(ax0, wf0c, dd[0]);                                      \
        dd[1]  = mfma16(ax1, wf0c, dd[1]);                                      \
      } else {                                                                  \
        _Pragma("unroll") for (int ki = 0; ki < 4; ++ki) {                      \
          bf16x8 q0 = *(bf16x8*)(sm + H1B_OFF + (P)*8192 + arow0 + ad[ki]);     \
          bf16x8 q1 = *(bf16x8*)(sm + H1B_OFF + (P)*8192 + arow1 + ad[ki]);     \
          bf16x8 w0 = *(bf16x8*)(sm + W1_OFF + brow0 + ad[ki]);                 \
          bf16x8 w1 = *(bf16x8*)(sm + W1_OFF + brow1 + ad[ki]);                 \
          bf16x8 w2 = *(bf16x8*)(sm + W1_OFF + brow2 + ad[ki]);                 \
          rzr[0] = mfma16(q0, w0, rzr[0]);                                      \
          rzr[1] = mfma16(q1, w0, rzr[1]);                                      \
          rzz[0] = mfma16(q0, w1, rzz[0]);                                      \
          rzz[1] = mfma16(q1, w1, rzz[1]);                                      \
          dd[0]  = mfma16(q0, w2, dd[0]);                                       \
          dd[1]  = mfma16(q1, w2, dd[1]);                                       \
        }                                                                       \
      }                                                                         \
      const int wbase = (P) ? wb1 : wb0;                                        \
      _Pragma("unroll") for (int mt = 0; mt < 2; ++mt)                          \
      _Pragma("unroll") for (int r = 0; r < 4; ++r) {                           \
        int s = mt*4 + r;                                                       \
        float rr = sigm(rzr[mt][r]);                                            \
        float zz = sigm(rzz[mt][r]);                                            \
        float iv = isL0 ? dd[mt][r] : cc[mt][r];                                \
        float hv = isL0 ? cc[mt][r] : dd[mt][r];                                \
        float nn = tanh_(__builtin_fmaf(rr, hv, iv));                           \
        float h = hs[s]; h = __builtin_fmaf(zz, h - nn, nn); hs[s] = h;         \
        *(u16*)(sm + wbase + st[s]) = f2bf(h);                                  \
      }                                                                         \
    }                                                                           \
    __syncthreads();                                                            \
  }

__global__ __attribute__((amdgpu_flat_work_group_size(1024, 1024)))
void k_gru(const float* __restrict__ x,
           const float* __restrict__ wih0, const float* __restrict__ whh0,
           const float* __restrict__ bih0, const float* __restrict__ bhh0,
           const float* __restrict__ wih1, const float* __restrict__ whh1,
           const float* __restrict__ bih1, const float* __restrict__ bhh1,
           float* __restrict__ hraw) {
  extern __shared__ char sm[];
  const int tid = threadIdx.x;
  const int wid = tid >> 6;
  const bool isL0 = wid < 8;
  const int lane = tid & 63;
  const int lq = lane >> 4;
  const int ul = lane & 15;
  const int u  = (wid & 7) * 16 + ul;   // hidden unit owned (within role)
  const int n0 = blockIdx.x * 32;
  const int sx = (ul & 7) << 4;

  // zero h0b/h1b/xbuf (36864 B)
  for (int idx = tid; idx < 9216; idx += 1024)
    *(float*)(sm + H0B_OFF + idx * 4) = 0.f;
  // stage W_hh1 fp32->bf16 into LDS, swizzled (used by L1 waves)
  for (int idx = tid; idx < 12288; idx += 1024) {
    int g = idx >> 5, c4 = (idx & 31) * 4;
    float4 v = *(const float4*)(whh1 + g * 128 + c4);
    unsigned int p0 = (unsigned int)f2bf(v.x) | ((unsigned int)f2bf(v.y) << 16);
    unsigned int p1 = (unsigned int)f2bf(v.z) | ((unsigned int)f2bf(v.w) << 16);
    unsigned int* dst = (unsigned int*)(sm + W1_OFF + g * 256 + ((c4 * 2) ^ ((g & 7) << 4)));
    dst[0] = p0; dst[1] = p1;
  }

  // role-shared register weight array: W_hh0 for L0 waves, W_ih1 for L1 waves
  const float* wsrc = isL0 ? whh0 : wih1;
  bf16x8 wfrag[3][4];
#pragma unroll
  for (int i = 0; i < 3; ++i) {
    int g = u + 128 * i;
#pragma unroll
    for (int ki = 0; ki < 4; ++ki)
      wfrag[i][ki] = pack8(wsrc + g * 128 + ki * 32 + lq * 8);
  }
  // W_ih0 hi/lo fragments (only used by L0 waves; loaded by all, shares regs)
  bf16x8 wf0a, wf0b, wf0c;
  {
    u16 t0[8] = {0,0,0,0,0,0,0,0}, t1[8] = {0,0,0,0,0,0,0,0}, t2[8] = {0,0,0,0,0,0,0,0};
    u16* ts[3] = {t0, t1, t2};
#pragma unroll
    for (int i = 0; i < 3; ++i) {
      int g = u + 128 * i;
      if (lq < 2) {
        for (int d = 0; d < 6; ++d) ts[i][d] = f2bf(wih0[g * 6 + d]);
      } else if (lq == 2) {
        for (int d = 0; d < 6; ++d) {
          float w = wih0[g * 6 + d];
          u16 h = f2bf(w);
          ts[i][d] = f2bf(w - bf2f(h));
        }
      }
    }
    wf0a = *(bf16x8*)t0; wf0b = *(bf16x8*)t1; wf0c = *(bf16x8*)t2;
  }
  // role-dependent biases (r,z folded; cc/dd = role-specific n-parts)
  const float brzr = isL0 ? (bih0[u] + bhh0[u]) : (bih1[u] + bhh1[u]);
  const float brzz = isL0 ? (bih0[u + 128] + bhh0[u + 128]) : (bih1[u + 128] + bhh1[u + 128]);
  const float bcc  = isL0 ? bhh0[u + 256] : bih1[u + 256];
  const float bdd  = isL0 ? bih0[u + 256] : bhh1[u + 256];

  int ad[4];
#pragma unroll
  for (int ki = 0; ki < 4; ++ki) ad[ki] = (ki * 64 + lq * 16) ^ sx;
  const int arow0 = ul * 256, arow1 = arow0 + 4096;
  const int xr0 = ul * 64 + lq * 16, xr1 = xr0 + 1024;
  const int brow0 = u * 256;
  const int brow1 = (u + 128) * 256;
  const int brow2 = (u + 256) * 256;
  int st[8];
#pragma unroll
  for (int mt = 0; mt < 2; ++mt)
#pragma unroll
    for (int r = 0; r < 4; ++r) {
      int m = mt * 16 + lq * 4 + r;
      st[mt * 4 + r] = m * 256 + ((u * 2) ^ ((m & 7) << 4));
    }
  // per-parity write bases: L0 writes h0b[P]; L1 writes h1b[P^1]
  const int wb0 = isL0 ? (H0B_OFF + 0)    : (H1B_OFF + 8192);
  const int wb1 = isL0 ? (H0B_OFF + 8192) : (H1B_OFF + 0);

  float hs[8];
#pragma unroll
  for (int s = 0; s < 8; ++s) hs[s] = 0.f;

  // x loaders: threads 0-191 (all in L0 waves)
  const int xm = tid / 6, xd = tid - 6 * xm;
  const bool xact = tid < 192;
  const float* gx = x + (size_t)(n0 + xm) * 384 + xd * 64;

  __syncthreads();  // zeros/W1 staging visible

  float xv = 0.f;
  if (xact) {
    float x0 = gx[0];
    u16 h = f2bf(x0);
    u16 l = f2bf(x0 - bf2f(h));
    char* p = sm + XB_OFF + xm * 64 + xd * 2;
    *(u16*)p = h; *(u16*)(p + 16) = l; *(u16*)(p + 32) = h;
    xv = gx[1];
  }
  __syncthreads();  // x(0) visible

  for (int k = 0; k < 64; k += 2) {
    FITER(0, k)
    FITER(1, k + 1)
  }
  FITER(0, 64)  // L1 finishes h1(63)

  // L1 threads hold final h1 in registers
  if (!isL0) {
#pragma unroll
    for (int mt = 0; mt < 2; ++mt)
#pragma unroll
      for (int r = 0; r < 4; ++r) {
        int m = mt * 16 + lq * 4 + r;
        hraw[(size_t)(n0 + m) * 128 + u] = hs[mt * 4 + r];
      }
  }
}

// ------------------------- BN1 partials (coalesced) -------------------------
__global__ void k_bn1p(const float* __restrict__ hraw, float* __restrict__ p) {
  __shared__ float s0[256], s1[256];
  int tid = threadIdx.x, b = blockIdx.x;
  int f = tid & 127, r = tid >> 7;
  float s = 0.f, q = 0.f;
  for (int n = b * 64 + r; n < b * 64 + 64; n += 2) {
    float v = hraw[(size_t)n * 128 + f];
    s += v; q += v * v;
  }
  s0[tid] = s; s1[tid] = q;
  __syncthreads();
  if (tid < 128) {
    p[b * 256 + tid] = s0[tid] + s0[tid + 128];
    p[b * 256 + 128 + tid] = s1[tid] + s1[tid + 128];
  }
}

__global__ void k_bn1r(const float* __restrict__ p, float* __restrict__ mu1,
                       float* __restrict__ rs1) {
  int f = threadIdx.x;
  float s = 0.f, q = 0.f;
  for (int b = 0; b < 128; ++b) { s += p[b * 256 + f]; q += p[b * 256 + 128 + f]; }
  float mu = s / 8192.f, var = q / 8192.f - mu * mu;
  mu1[f] = mu; rs1[f] = rsqrtf(var + 1e-5f);
}

// ------------------------- BN1 apply + row means + Gram/mh partials -------------------------
__global__ void k_attp(const float* __restrict__ hraw, const float* __restrict__ mu1,
                       const float* __restrict__ rs1, const float* __restrict__ g1,
                       const float* __restrict__ b1, float* __restrict__ hidden,
                       float* __restrict__ mvec, float* __restrict__ gpart,
                       float* __restrict__ mhpart) {
  __shared__ float hid[64][128];
  __shared__ float mld[64];
  int tid = threadIdx.x, blk = blockIdx.x, n0 = blk * 64;
  for (int idx = tid; idx < 64 * 128; idx += 256) {
    int n = idx >> 7, f = idx & 127;
    float v = (hraw[(size_t)(n0 + n) * 128 + f] - mu1[f]) * rs1[f] * g1[f] + b1[f];
    hid[n][f] = v;
    hidden[(size_t)(n0 + n) * 128 + f] = v;
  }
  __syncthreads();
  if (tid < 64) {
    float s = 0.f;
    for (int f = 0; f < 128; ++f) s += hid[tid][f];
    s *= (1.f / 128.f);
    mld[tid] = s; mvec[n0 + tid] = s;
  }
  __syncthreads();
  int i = tid >> 1, j0 = (tid & 1) * 64;
  float acc[64];
#pragma unroll
  for (int j = 0; j < 64; ++j) acc[j] = 0.f;
  for (int n = 0; n < 64; ++n) {
    float a = hid[n][i];
#pragma unroll
    for (int j = 0; j < 64; ++j) acc[j] += a * hid[n][j0 + j];
  }
#pragma unroll
  for (int j = 0; j < 64; ++j) gpart[(size_t)blk * 16384 + i * 128 + j0 + j] = acc[j];
  if (tid < 128) {
    float s = 0.f;
    for (int n = 0; n < 64; ++n) s += mld[n] * hid[n][tid];
    mhpart[blk * 128 + tid] = s;
  }
}

// ------------------------- reduce Gram/mh partials -------------------------
__global__ void k_attfa(const float* __restrict__ gpart, const float* __restrict__ mhpart,
                        float* __restrict__ gfull, float* __restrict__ mhfull) {
  int idx = blockIdx.x * 256 + threadIdx.x;
  float s = 0.f;
  for (int b = 0; b < 128; ++b) s += gpart[(size_t)b * 16384 + idx];
  gfull[idx] = s;
  if (blockIdx.x == 0 && threadIdx.x < 128) {
    float t = 0.f;
    for (int b = 0; b < 128; ++b) t += mhpart[b * 128 + threadIdx.x];
    mhfull[threadIdx.x] = t;
  }
}

// ------------------------- M2 = (G/H) @ fc_w^T ; u = mh @ fc_w^T -------------------------
__global__ void k_attfb(const float* __restrict__ gfull, const float* __restrict__ mhfull,
                        const float* __restrict__ fcw, float* __restrict__ m2,
                        float* __restrict__ uvec) {
  int idx = blockIdx.x * 128 + threadIdx.x;
  int k = idx >> 7, j = idx & 127;
  const float4* ga = (const float4*)(gfull + k * 128);
  const float4* fb = (const float4*)(fcw + j * 128);
  float a0 = 0.f, a1 = 0.f, a2 = 0.f, a3 = 0.f;
#pragma unroll 8
  for (int f = 0; f < 32; ++f) {
    float4 a = ga[f], b = fb[f];
    a0 += a.x * b.x; a1 += a.y * b.y; a2 += a.z * b.z; a3 += a.w * b.w;
  }
  m2[idx] = (a0 + a1 + a2 + a3) * (1.f / 128.f);
  if (idx < 128) {
    float s = 0.f;
    const float* fr = fcw + idx * 128;
#pragma unroll 8
    for (int f = 0; f < 128; ++f) s += mhfull[f] * fr[f];
    uvec[idx] = s;
  }
}

// ------------------------- out2 = hidden@M2 - m*u + fc_b ; BN2 partials -------------------------
__global__ void k_out2(const float* __restrict__ hidden, const float* __restrict__ mvec,
                       const float* __restrict__ m2g, const float* __restrict__ uvec,
                       const float* __restrict__ fcb, float* __restrict__ out2,
                       float* __restrict__ bn2p) {
  extern __shared__ char smo[];
  float* m2l = (float*)smo;
  float* hl = m2l + 16384;
  float* ml = hl + 4096;
  float* red = ml + 32;
  int tid = threadIdx.x, blk = blockIdx.x, n0 = blk * 32;
  for (int idx = tid; idx < 16384; idx += 256) m2l[idx] = m2g[idx];
  for (int idx = tid; idx < 4096; idx += 256) hl[idx] = hidden[(size_t)n0 * 128 + idx];
  if (tid < 32) ml[tid] = mvec[n0 + tid];
  __syncthreads();
  int j = tid & 127, rg = tid >> 7;
  float uj = uvec[j], bj = fcb[j];
  float s1 = 0.f, s2 = 0.f;
  for (int q = 0; q < 16; ++q) {
    int nl = rg * 16 + q;
    float s = bj - ml[nl] * uj;
    const float* hr = hl + nl * 128;
#pragma unroll 8
    for (int k = 0; k < 128; ++k) s += hr[k] * m2l[k * 128 + j];
    out2[(size_t)(n0 + nl) * 128 + j] = s;
    s1 += s; s2 += s * s;
  }
  red[tid] = s1; red[256 + tid] = s2;
  __syncthreads();
  if (tid < 128) {
    bn2p[blk * 256 + tid] = red[tid] + red[128 + tid];
    bn2p[blk * 256 + 128 + tid] = red[256 + tid] + red[384 + tid];
  }
}

// ------------------------- BN2 stats -------------------------
__global__ void k_bn2(const float* __restrict__ bn2p, float* __restrict__ mu2,
                      float* __restrict__ rs2) {
  int j = threadIdx.x;
  float s = 0.f, q = 0.f;
  for (int b = 0; b < 256; ++b) {
    s += bn2p[b * 256 + j];
    q += bn2p[b * 256 + 128 + j];
  }
  float mu = s / 8192.f, var = q / 8192.f - mu * mu;
  mu2[j] = mu; rs2[j] = rsqrtf(var + 1e-5f);
}

// ------------------------- BN2 apply + leaky-relu + final GEMV -------------------------
__global__ void k_fin(const float* __restrict__ out2, const float* __restrict__ mu2,
                      const float* __restrict__ rs2, const float* __restrict__ g2,
                      const float* __restrict__ b2, const float* __restrict__ fcow,
                      const float* __restrict__ fcob, float* __restrict__ y) {
  int tid = threadIdx.x, lane = tid & 63, w = tid >> 6;
  int n = blockIdx.x * 4 + w;
  float s = 0.f;
#pragma unroll
  for (int h = 0; h < 2; ++h) {
    int j = lane + h * 64;
    float v = (out2[(size_t)n * 128 + j] - mu2[j]) * rs2[j] * g2[j] + b2[j];
    v = fmaxf(v, 0.01f * v);
    s += v * fcow[j];
  }
  for (int off = 32; off; off >>= 1) s += __shfl_down(s, off);
  if (!lane) y[n] = s + fcob[0];
}

// ------------------------- launch -------------------------
extern "C" void kernel_launch(void* const* d_in, const int* in_sizes, int n_in,
                              void* d_out, int out_size, void* d_ws, size_t ws_size,
                              hipStream_t stream) {
  const float* x    = (const float*)d_in[0];
  const float* wih0 = (const float*)d_in[1];
  const float* whh0 = (const float*)d_in[2];
  const float* bih0 = (const float*)d_in[3];
  const float* bhh0 = (const float*)d_in[4];
  const float* wih1 = (const float*)d_in[5];
  const float* whh1 = (const float*)d_in[6];
  const float* bih1 = (const float*)d_in[7];
  const float* bhh1 = (const float*)d_in[8];
  const float* g1   = (const float*)d_in[9];
  const float* b1   = (const float*)d_in[10];
  const float* fcw  = (const float*)d_in[11];
  const float* fcb  = (const float*)d_in[12];
  const float* g2   = (const float*)d_in[13];
  const float* b2   = (const float*)d_in[14];
  const float* fcow = (const float*)d_in[15];
  const float* fcob = (const float*)d_in[16];

  char* ws = (char*)d_ws;
  float* hraw   = (float*)(ws + 0);
  float* hidden = (float*)(ws + 4194304);
  float* mvec   = (float*)(ws + 8388608);
  float* mu1    = (float*)(ws + 8421376);
  float* rs1    = (float*)(ws + 8421888);
  float* gpart  = (float*)(ws + 8422400);
  float* mhpart = (float*)(ws + 16811008);
  float* m2     = (float*)(ws + 16876544);
  float* uvec   = (float*)(ws + 16942080);
  float* out2   = (float*)(ws + 16942592);
  float* bn2p   = (float*)(ws + 21136896);  // reused: bn1 partials live here first
  float* mu2    = (float*)(ws + 21399040);
  float* rs2    = (float*)(ws + 21399552);
  float* gfull  = (float*)(ws + 21400064);
  float* mhfull = (float*)(ws + 21465600);

  (void)hipFuncSetAttribute((const void*)k_gru,
                            hipFuncAttributeMaxDynamicSharedMemorySize, GRU_LDS);
  (void)hipFuncSetAttribute((const void*)k_out2,
                            hipFuncAttributeMaxDynamicSharedMemorySize, 84096);

  k_gru<<<256, 1024, GRU_LDS, stream>>>(x, wih0, whh0, bih0, bhh0, wih1, whh1,
                                        bih1, bhh1, hraw);
  k_bn1p<<<128, 256, 0, stream>>>(hraw, bn2p);
  k_bn1r<<<1, 128, 0, stream>>>(bn2p, mu1, rs1);
  k_attp<<<128, 256, 0, stream>>>(hraw, mu1, rs1, g1, b1, hidden, mvec, gpart, mhpart);
  k_attfa<<<64, 256, 0, stream>>>(gpart, mhpart, gfull, mhfull);
  k_attfb<<<128, 128, 0, stream>>>(gfull, mhfull, fcw, m2, uvec);
  k_out2<<<256, 256, 84096, stream>>>(hidden, mvec, m2, uvec, fcb, out2, bn2p);
  k_bn2<<<1, 128, 0, stream>>>(bn2p, mu2, rs2);
  k_fin<<<2048, 256, 0, stream>>>(out2, mu2, rs2, g2, b2, fcow, fcob, (float*)d_out);
}

// Round 8
// 342.518 us; speedup vs baseline: 1.8253x; 1.8253x over previous
//
#include <hip/hip_runtime.h>

typedef unsigned short u16;
typedef short bf16x8 __attribute__((ext_vector_type(8)));
typedef float f32x4 __attribute__((ext_vector_type(4)));

#define NBATCH 8192

__device__ __forceinline__ f32x4 mfma16(bf16x8 a, bf16x8 b, f32x4 c) {
  return __builtin_amdgcn_mfma_f32_16x16x32_bf16(a, b, c, 0, 0, 0);
}
__device__ __forceinline__ u16 f2bf(float f) {
  unsigned int u = __float_as_uint(f);
  return (u16)((u + 0x7FFFu + ((u >> 16) & 1u)) >> 16);
}
__device__ __forceinline__ float bf2f(u16 h) {
  return __uint_as_float(((unsigned int)h) << 16);
}
__device__ __forceinline__ float sigm(float x) {
  return __builtin_amdgcn_rcpf(1.f + __builtin_amdgcn_exp2f(-1.44269504f * x));
}
__device__ __forceinline__ float tanh_(float x) {
  float t = __builtin_amdgcn_exp2f(2.88539008f * x);
  return 1.f - 2.f * __builtin_amdgcn_rcpf(t + 1.f);
}
__device__ __forceinline__ bf16x8 pack8(const float* p) {
  float4 a = *(const float4*)p, b = *(const float4*)(p + 4);
  bf16x8 r;
  r[0] = (short)f2bf(a.x); r[1] = (short)f2bf(a.y);
  r[2] = (short)f2bf(a.z); r[3] = (short)f2bf(a.w);
  r[4] = (short)f2bf(b.x); r[5] = (short)f2bf(b.y);
  r[6] = (short)f2bf(b.z); r[7] = (short)f2bf(b.w);
  return r;
}

// =====================================================================
// R7 post-mortem: the allocator hard-targets 2 blocks/CU (512thr->128
// VGPR, 1024thr->64) and no attribute overrides it. So: make the
// 2-blocks/CU assumption TRUE. Layer-split kernels, 512 blocks x 16
// samples, 8 waves; only W_hh[r,z] in LDS (64K), n-gate rows + (for L1)
// W_ih1 in registers. LDS 74/76K -> 2 blocks/CU co-resident -> 4
// waves/SIMD (2x all previous rounds); VGPR demand ~85/~118 <= 128
// budget -> no spills. Numerics bit-identical to R3-R6.
// =====================================================================

// ---------------- k_gru0: layer-0 recurrence ----------------
// LDS: W_hh0[r,z] 64K | h0b dbuf 2x4K | x dbuf 2x1K = 74K
#define A_WRZ  0
#define A_H0B  65536
#define A_XB   73728
#define A_LDS  75776

#define GRU0_STEP(RD, WR, T)                                                    \
  {                                                                             \
    if (xact && (T) < 63) {                                                     \
      u16 xh = f2bf(xv);                                                        \
      u16 xl = f2bf(xv - bf2f(xh));                                             \
      char* xw = sm + A_XB + (WR)*1024 + xm*64 + xd*2;                          \
      *(u16*)xw = xh; *(u16*)(xw + 16) = xl; *(u16*)(xw + 32) = xh;             \
      if ((T) < 62) xv = gx[(T) + 2];                                           \
    }                                                                           \
    f32x4 accr = {brzr, brzr, brzr, brzr};                                      \
    f32x4 accz = {brzz, brzz, brzz, brzz};                                      \
    f32x4 acch = {bhn0, bhn0, bhn0, bhn0};                                      \
    f32x4 acci = {bin0, bin0, bin0, bin0};                                      \
    _Pragma("unroll") for (int ki = 0; ki < 4; ++ki) {                          \
      bf16x8 a0 = *(bf16x8*)(sm + A_H0B + (RD)*4096 + arow0 + ad[ki]);          \
      bf16x8 br = *(bf16x8*)(sm + A_WRZ + browr + ad[ki]);                      \
      bf16x8 bz = *(bf16x8*)(sm + A_WRZ + browz + ad[ki]);                      \
      accr = mfma16(a0, br, accr);                                              \
      accz = mfma16(a0, bz, accz);                                              \
      acch = mfma16(a0, wn0[ki], acch);                                         \
    }                                                                           \
    {                                                                           \
      bf16x8 ax0 = *(bf16x8*)(sm + A_XB + (RD)*1024 + xr0);                     \
      accr = mfma16(ax0, wf0a, accr);                                           \
      accz = mfma16(ax0, wf0b, accz);                                           \
      acci = mfma16(ax0, wf0c, acci);                                           \
    }                                                                           \
    if ((T) >= 1) { /* stream h0(T-1) swizzled tile to global, verbatim */      \
      uint2 gv = *(const uint2*)(sm + A_H0B + (RD)*4096 + tid*8);               \
      *(uint2*)(h0seq + (size_t)((T)-1)*2097152 + gofs) = gv;                   \
    }                                                                           \
    _Pragma("unroll") for (int r = 0; r < 4; ++r) {                             \
      float rr = sigm(accr[r]);                                                 \
      float zz = sigm(accz[r]);                                                 \
      float nn = tanh_(__builtin_fmaf(rr, acch[r], acci[r]));                   \
      float h = h0s[r]; h = __builtin_fmaf(zz, h - nn, nn); h0s[r] = h;         \
      *(u16*)(sm + A_H0B + (WR)*4096 + st[r]) = f2bf(h);                        \
    }                                                                           \
    __syncthreads();                                                            \
  }

__global__ __attribute__((amdgpu_flat_work_group_size(512, 512)))
void k_gru0(const float* __restrict__ x,
            const float* __restrict__ wih0, const float* __restrict__ whh0,
            const float* __restrict__ bih0, const float* __restrict__ bhh0,
            char* __restrict__ h0seq) {
  extern __shared__ char sm[];
  const int tid = threadIdx.x;
  const int wid = tid >> 6;
  const int lane = tid & 63;
  const int lq = lane >> 4;
  const int ul = lane & 15;
  const int u  = wid * 16 + ul;
  const int n0 = blockIdx.x * 16;
  const int sx = (ul & 7) << 4;
  const int gofs = blockIdx.x * 4096 + tid * 8;

  // zero h0b dbuf + x dbuf (10240 B)
  for (int idx = tid; idx < 2560; idx += 512)
    *(float*)(sm + A_H0B + idx * 4) = 0.f;
  // stage W_hh0 rows 0..255 (r,z) fp32->bf16, swizzled
  for (int idx = tid; idx < 8192; idx += 512) {
    int g = idx >> 5, c4 = (idx & 31) * 4;
    float4 v = *(const float4*)(whh0 + g * 128 + c4);
    unsigned int p0 = (unsigned int)f2bf(v.x) | ((unsigned int)f2bf(v.y) << 16);
    unsigned int p1 = (unsigned int)f2bf(v.z) | ((unsigned int)f2bf(v.w) << 16);
    unsigned int* dst = (unsigned int*)(sm + A_WRZ + g * 256 + ((c4 * 2) ^ ((g & 7) << 4)));
    dst[0] = p0; dst[1] = p1;
  }
  // n-gate rows (256+u) in registers
  bf16x8 wn0[4];
#pragma unroll
  for (int ki = 0; ki < 4; ++ki)
    wn0[ki] = pack8(whh0 + (256 + u) * 128 + ki * 32 + lq * 8);

  // W_ih0 hi/lo fragments (k0-5: whi for x-hi; k8-13: whi for x-lo; k16-21: wlo)
  bf16x8 wf0a, wf0b, wf0c;
  {
    u16 t0[8] = {0,0,0,0,0,0,0,0}, t1[8] = {0,0,0,0,0,0,0,0}, t2[8] = {0,0,0,0,0,0,0,0};
    u16* ts[3] = {t0, t1, t2};
#pragma unroll
    for (int i = 0; i < 3; ++i) {
      int g = u + 128 * i;
      if (lq < 2) {
        for (int d = 0; d < 6; ++d) ts[i][d] = f2bf(wih0[g * 6 + d]);
      } else if (lq == 2) {
        for (int d = 0; d < 6; ++d) {
          float w = wih0[g * 6 + d];
          u16 h = f2bf(w);
          ts[i][d] = f2bf(w - bf2f(h));
        }
      }
    }
    wf0a = *(bf16x8*)t0; wf0b = *(bf16x8*)t1; wf0c = *(bf16x8*)t2;
  }
  const float brzr = bih0[u] + bhh0[u];
  const float brzz = bih0[u + 128] + bhh0[u + 128];
  const float bin0 = bih0[u + 256], bhn0 = bhh0[u + 256];

  int ad[4];
#pragma unroll
  for (int ki = 0; ki < 4; ++ki) ad[ki] = (ki * 64 + lq * 16) ^ sx;
  const int arow0 = ul * 256;
  const int xr0 = ul * 64 + lq * 16;
  const int browr = u * 256;
  const int browz = (u + 128) * 256;
  int st[4];
#pragma unroll
  for (int r = 0; r < 4; ++r) {
    int m = lq * 4 + r;
    st[r] = m * 256 + ((u * 2) ^ ((m & 7) << 4));
  }

  float h0s[4];
#pragma unroll
  for (int r = 0; r < 4; ++r) h0s[r] = 0.f;

  // x loaders: 96 threads own one (sample, feature) pair
  const int xm = tid / 6, xd = tid - 6 * xm;
  const bool xact = tid < 96;
  const float* gx = x + (size_t)(n0 + xm) * 384 + xd * 64;

  __syncthreads();  // zeros/weights visible

  float xv = 0.f;
  if (xact) {
    float x0 = gx[0];
    u16 h = f2bf(x0);
    u16 l = f2bf(x0 - bf2f(h));
    char* p = sm + A_XB + xm * 64 + xd * 2;
    *(u16*)p = h; *(u16*)(p + 16) = l; *(u16*)(p + 32) = h;
    xv = gx[1];
  }
  __syncthreads();  // x(0) visible

  for (int t = 0; t < 64; t += 2) {
    GRU0_STEP(0, 1, t)
    GRU0_STEP(1, 0, t + 1)
  }
  // epilogue: h0(63) sits in buf0
  {
    uint2 gv = *(const uint2*)(sm + A_H0B + tid * 8);
    *(uint2*)(h0seq + (size_t)63 * 2097152 + gofs) = gv;
  }
}

// ---------------- k_gru1: layer-1 recurrence ----------------
// LDS: W_hh1[r,z] 64K | h0in dbuf 2x4K | h1b single 4K = 76K
#define B_WRZ  0
#define B_H0IN 65536
#define B_H1B  73728
#define B_LDS  77824

#define GRU1_STEP(P, T)                                                         \
  {                                                                             \
    uint2 hv = {0u, 0u};                                                        \
    if ((T) < 63) hv = *(const uint2*)(gsrc + (size_t)((T)+1)*2097152);         \
    f32x4 accr = {brzr, brzr, brzr, brzr};                                      \
    f32x4 accz = {brzz, brzz, brzz, brzz};                                      \
    f32x4 acci = {bin1, bin1, bin1, bin1};                                      \
    f32x4 acch = {bhn1, bhn1, bhn1, bhn1};                                      \
    _Pragma("unroll") for (int ki = 0; ki < 4; ++ki) {                          \
      bf16x8 p0 = *(bf16x8*)(sm + B_H0IN + (P)*4096 + arow0 + ad[ki]);          \
      bf16x8 q0 = *(bf16x8*)(sm + B_H1B + arow0 + ad[ki]);                      \
      bf16x8 br = *(bf16x8*)(sm + B_WRZ + browr + ad[ki]);                      \
      bf16x8 bz = *(bf16x8*)(sm + B_WRZ + browz + ad[ki]);                      \
      accr = mfma16(p0, wih1f[0][ki], accr);                                    \
      accr = mfma16(q0, br, accr);                                              \
      accz = mfma16(p0, wih1f[1][ki], accz);                                    \
      accz = mfma16(q0, bz, accz);                                              \
      acci = mfma16(p0, wih1f[2][ki], acci);                                    \
      acch = mfma16(q0, wn1[ki], acch);                                         \
    }                                                                           \
    u16 hw[4];                                                                  \
    _Pragma("unroll") for (int r = 0; r < 4; ++r) {                             \
      float rr = sigm(accr[r]);                                                 \
      float zz = sigm(accz[r]);                                                 \
      float nn = tanh_(__builtin_fmaf(rr, acch[r], acci[r]));                   \
      float h = h1s[r]; h = __builtin_fmaf(zz, h - nn, nn); h1s[r] = h;         \
      hw[r] = f2bf(h);                                                          \
    }                                                                           \
    __syncthreads();  /* B1: all reads of h1b / h0in[P^1] done */               \
    if ((T) < 63) *(uint2*)(sm + B_H0IN + ((P)^1)*4096 + tid*8) = hv;           \
    _Pragma("unroll") for (int r = 0; r < 4; ++r)                               \
      *(u16*)(sm + B_H1B + st[r]) = hw[r];                                      \
    __syncthreads();  /* B2: h1(T), h0(T+1) visible */                          \
  }

__global__ __attribute__((amdgpu_flat_work_group_size(512, 512)))
void k_gru1(const float* __restrict__ wih1, const float* __restrict__ whh1,
            const float* __restrict__ bih1, const float* __restrict__ bhh1,
            const char* __restrict__ h0seq, float* __restrict__ hraw) {
  extern __shared__ char sm[];
  const int tid = threadIdx.x;
  const int wid = tid >> 6;
  const int lane = tid & 63;
  const int lq = lane >> 4;
  const int ul = lane & 15;
  const int u  = wid * 16 + ul;
  const int n0 = blockIdx.x * 16;
  const int sx = (ul & 7) << 4;
  const char* gsrc = h0seq + blockIdx.x * 4096 + tid * 8;

  // zero h1b (4KB)
  for (int idx = tid; idx < 1024; idx += 512)
    *(float*)(sm + B_H1B + idx * 4) = 0.f;
  // stage W_hh1 rows 0..255 (r,z) fp32->bf16, swizzled
  for (int idx = tid; idx < 8192; idx += 512) {
    int g = idx >> 5, c4 = (idx & 31) * 4;
    float4 v = *(const float4*)(whh1 + g * 128 + c4);
    unsigned int p0 = (unsigned int)f2bf(v.x) | ((unsigned int)f2bf(v.y) << 16);
    unsigned int p1 = (unsigned int)f2bf(v.z) | ((unsigned int)f2bf(v.w) << 16);
    unsigned int* dst = (unsigned int*)(sm + B_WRZ + g * 256 + ((c4 * 2) ^ ((g & 7) << 4)));
    dst[0] = p0; dst[1] = p1;
  }
  // h0(0) into h0in buf0 (verbatim copy of k_gru0's swizzled tile)
  {
    uint2 h0v = *(const uint2*)(gsrc);
    *(uint2*)(sm + B_H0IN + tid * 8) = h0v;
  }
  // register weights: W_ih1 rows {u, u+128, u+256}; W_hh1 n-row (256+u)
  bf16x8 wih1f[3][4], wn1[4];
#pragma unroll
  for (int i = 0; i < 3; ++i) {
    int g = u + 128 * i;
#pragma unroll
    for (int ki = 0; ki < 4; ++ki)
      wih1f[i][ki] = pack8(wih1 + g * 128 + ki * 32 + lq * 8);
  }
#pragma unroll
  for (int ki = 0; ki < 4; ++ki)
    wn1[ki] = pack8(whh1 + (256 + u) * 128 + ki * 32 + lq * 8);

  const float brzr = bih1[u] + bhh1[u];
  const float brzz = bih1[u + 128] + bhh1[u + 128];
  const float bin1 = bih1[u + 256], bhn1 = bhh1[u + 256];

  int ad[4];
#pragma unroll
  for (int ki = 0; ki < 4; ++ki) ad[ki] = (ki * 64 + lq * 16) ^ sx;
  const int arow0 = ul * 256;
  const int browr = u * 256;
  const int browz = (u + 128) * 256;
  int st[4];
#pragma unroll
  for (int r = 0; r < 4; ++r) {
    int m = lq * 4 + r;
    st[r] = m * 256 + ((u * 2) ^ ((m & 7) << 4));
  }

  float h1s[4];
#pragma unroll
  for (int r = 0; r < 4; ++r) h1s[r] = 0.f;

  __syncthreads();  // staging visible

  for (int t = 0; t < 64; t += 2) {
    GRU1_STEP(0, t)
    GRU1_STEP(1, t + 1)
  }

#pragma unroll
  for (int r = 0; r < 4; ++r) {
    int m = lq * 4 + r;
    hraw[(size_t)(n0 + m) * 128 + u] = h1s[r];
  }
}

// ------------------------- BN1 partials (coalesced) -------------------------
__global__ void k_bn1p(const float* __restrict__ hraw, float* __restrict__ p) {
  __shared__ float s0[256], s1[256];
  int tid = threadIdx.x, b = blockIdx.x;
  int f = tid & 127, r = tid >> 7;
  float s = 0.f, q = 0.f;
  for (int n = b * 64 + r; n < b * 64 + 64; n += 2) {
    float v = hraw[(size_t)n * 128 + f];
    s += v; q += v * v;
  }
  s0[tid] = s; s1[tid] = q;
  __syncthreads();
  if (tid < 128) {
    p[b * 256 + tid] = s0[tid] + s0[tid + 128];
    p[b * 256 + 128 + tid] = s1[tid] + s1[tid + 128];
  }
}

__global__ void k_bn1r(const float* __restrict__ p, float* __restrict__ mu1,
                       float* __restrict__ rs1) {
  int f = threadIdx.x;
  float s = 0.f, q = 0.f;
  for (int b = 0; b < 128; ++b) { s += p[b * 256 + f]; q += p[b * 256 + 128 + f]; }
  float mu = s / 8192.f, var = q / 8192.f - mu * mu;
  mu1[f] = mu; rs1[f] = rsqrtf(var + 1e-5f);
}

// ------------------------- BN1 apply + row means + Gram/mh partials -------------------------
__global__ void k_attp(const float* __restrict__ hraw, const float* __restrict__ mu1,
                       const float* __restrict__ rs1, const float* __restrict__ g1,
                       const float* __restrict__ b1, float* __restrict__ hidden,
                       float* __restrict__ mvec, float* __restrict__ gpart,
                       float* __restrict__ mhpart) {
  __shared__ float hid[64][128];
  __shared__ float mld[64];
  int tid = threadIdx.x, blk = blockIdx.x, n0 = blk * 64;
  for (int idx = tid; idx < 64 * 128; idx += 256) {
    int n = idx >> 7, f = idx & 127;
    float v = (hraw[(size_t)(n0 + n) * 128 + f] - mu1[f]) * rs1[f] * g1[f] + b1[f];
    hid[n][f] = v;
    hidden[(size_t)(n0 + n) * 128 + f] = v;
  }
  __syncthreads();
  if (tid < 64) {
    float s = 0.f;
    for (int f = 0; f < 128; ++f) s += hid[tid][f];
    s *= (1.f / 128.f);
    mld[tid] = s; mvec[n0 + tid] = s;
  }
  __syncthreads();
  int i = tid >> 1, j0 = (tid & 1) * 64;
  float acc[64];
#pragma unroll
  for (int j = 0; j < 64; ++j) acc[j] = 0.f;
  for (int n = 0; n < 64; ++n) {
    float a = hid[n][i];
#pragma unroll
    for (int j = 0; j < 64; ++j) acc[j] += a * hid[n][j0 + j];
  }
#pragma unroll
  for (int j = 0; j < 64; ++j) gpart[(size_t)blk * 16384 + i * 128 + j0 + j] = acc[j];
  if (tid < 128) {
    float s = 0.f;
    for (int n = 0; n < 64; ++n) s += mld[n] * hid[n][tid];
    mhpart[blk * 128 + tid] = s;
  }
}

// ------------------------- reduce Gram/mh partials -------------------------
__global__ void k_attfa(const float* __restrict__ gpart, const float* __restrict__ mhpart,
                        float* __restrict__ gfull, float* __restrict__ mhfull) {
  int idx = blockIdx.x * 256 + threadIdx.x;
  float s = 0.f;
  for (int b = 0; b < 128; ++b) s += gpart[(size_t)b * 16384 + idx];
  gfull[idx] = s;
  if (blockIdx.x == 0 && threadIdx.x < 128) {
    float t = 0.f;
    for (int b = 0; b < 128; ++b) t += mhpart[b * 128 + threadIdx.x];
    mhfull[threadIdx.x] = t;
  }
}

// ------------------------- M2 = (G/H) @ fc_w^T ; u = mh @ fc_w^T -------------------------
__global__ void k_attfb(const float* __restrict__ gfull, const float* __restrict__ mhfull,
                        const float* __restrict__ fcw, float* __restrict__ m2,
                        float* __restrict__ uvec) {
  int idx = blockIdx.x * 128 + threadIdx.x;
  int k = idx >> 7, j = idx & 127;
  const float4* ga = (const float4*)(gfull + k * 128);
  const float4* fb = (const float4*)(fcw + j * 128);
  float a0 = 0.f, a1 = 0.f, a2 = 0.f, a3 = 0.f;
#pragma unroll 8
  for (int f = 0; f < 32; ++f) {
    float4 a = ga[f], b = fb[f];
    a0 += a.x * b.x; a1 += a.y * b.y; a2 += a.z * b.z; a3 += a.w * b.w;
  }
  m2[idx] = (a0 + a1 + a2 + a3) * (1.f / 128.f);
  if (idx < 128) {
    float s = 0.f;
    const float* fr = fcw + idx * 128;
#pragma unroll 8
    for (int f = 0; f < 128; ++f) s += mhfull[f] * fr[f];
    uvec[idx] = s;
  }
}

// ------------------------- out2 = hidden@M2 - m*u + fc_b ; BN2 partials -------------------------
__global__ void k_out2(const float* __restrict__ hidden, const float* __restrict__ mvec,
                       const float* __restrict__ m2g, const float* __restrict__ uvec,
                       const float* __restrict__ fcb, float* __restrict__ out2,
                       float* __restrict__ bn2p) {
  extern __shared__ char smo[];
  float* m2l = (float*)smo;
  float* hl = m2l + 16384;
  float* ml = hl + 4096;
  float* red = ml + 32;
  int tid = threadIdx.x, blk = blockIdx.x, n0 = blk * 32;
  for (int idx = tid; idx < 16384; idx += 256) m2l[idx] = m2g[idx];
  for (int idx = tid; idx < 4096; idx += 256) hl[idx] = hidden[(size_t)n0 * 128 + idx];
  if (tid < 32) ml[tid] = mvec[n0 + tid];
  __syncthreads();
  int j = tid & 127, rg = tid >> 7;
  float uj = uvec[j], bj = fcb[j];
  float s1 = 0.f, s2 = 0.f;
  for (int q = 0; q < 16; ++q) {
    int nl = rg * 16 + q;
    float s = bj - ml[nl] * uj;
    const float* hr = hl + nl * 128;
#pragma unroll 8
    for (int k = 0; k < 128; ++k) s += hr[k] * m2l[k * 128 + j];
    out2[(size_t)(n0 + nl) * 128 + j] = s;
    s1 += s; s2 += s * s;
  }
  red[tid] = s1; red[256 + tid] = s2;
  __syncthreads();
  if (tid < 128) {
    bn2p[blk * 256 + tid] = red[tid] + red[128 + tid];
    bn2p[blk * 256 + 128 + tid] = red[256 + tid] + red[384 + tid];
  }
}

// ------------------------- BN2 stats -------------------------
__global__ void k_bn2(const float* __restrict__ bn2p, float* __restrict__ mu2,
                      float* __restrict__ rs2) {
  int j = threadIdx.x;
  float s = 0.f, q = 0.f;
  for (int b = 0; b < 256; ++b) {
    s += bn2p[b * 256 + j];
    q += bn2p[b * 256 + 128 + j];
  }
  float mu = s / 8192.f, var = q / 8192.f - mu * mu;
  mu2[j] = mu; rs2[j] = rsqrtf(var + 1e-5f);
}

// ------------------------- BN2 apply + leaky-relu + final GEMV -------------------------
__global__ void k_fin(const float* __restrict__ out2, const float* __restrict__ mu2,
                      const float* __restrict__ rs2, const float* __restrict__ g2,
                      const float* __restrict__ b2, const float* __restrict__ fcow,
                      const float* __restrict__ fcob, float* __restrict__ y) {
  int tid = threadIdx.x, lane = tid & 63, w = tid >> 6;
  int n = blockIdx.x * 4 + w;
  float s = 0.f;
#pragma unroll
  for (int h = 0; h < 2; ++h) {
    int j = lane + h * 64;
    float v = (out2[(size_t)n * 128 + j] - mu2[j]) * rs2[j] * g2[j] + b2[j];
    v = fmaxf(v, 0.01f * v);
    s += v * fcow[j];
  }
  for (int off = 32; off; off >>= 1) s += __shfl_down(s, off);
  if (!lane) y[n] = s + fcob[0];
}

// ------------------------- launch -------------------------
extern "C" void kernel_launch(void* const* d_in, const int* in_sizes, int n_in,
                              void* d_out, int out_size, void* d_ws, size_t ws_size,
                              hipStream_t stream) {
  const float* x    = (const float*)d_in[0];
  const float* wih0 = (const float*)d_in[1];
  const float* whh0 = (const float*)d_in[2];
  const float* bih0 = (const float*)d_in[3];
  const float* bhh0 = (const float*)d_in[4];
  const float* wih1 = (const float*)d_in[5];
  const float* whh1 = (const float*)d_in[6];
  const float* bih1 = (const float*)d_in[7];
  const float* bhh1 = (const float*)d_in[8];
  const float* g1   = (const float*)d_in[9];
  const float* b1   = (const float*)d_in[10];
  const float* fcw  = (const float*)d_in[11];
  const float* fcb  = (const float*)d_in[12];
  const float* g2   = (const float*)d_in[13];
  const float* b2   = (const float*)d_in[14];
  const float* fcow = (const float*)d_in[15];
  const float* fcob = (const float*)d_in[16];

  char* ws = (char*)d_ws;
  float* hraw   = (float*)(ws + 0);
  float* hidden = (float*)(ws + 4194304);
  float* mvec   = (float*)(ws + 8388608);
  float* mu1    = (float*)(ws + 8421376);
  float* rs1    = (float*)(ws + 8421888);
  float* gpart  = (float*)(ws + 8422400);
  float* mhpart = (float*)(ws + 16811008);
  float* m2     = (float*)(ws + 16876544);
  float* uvec   = (float*)(ws + 16942080);
  float* out2   = (float*)(ws + 16942592);
  float* bn2p   = (float*)(ws + 21136896);  // reused: bn1 partials live here first
  float* mu2    = (float*)(ws + 21399040);
  float* rs2    = (float*)(ws + 21399552);
  float* gfull  = (float*)(ws + 21400064);
  float* mhfull = (float*)(ws + 21465600);
  char*  h0seq  = (char*)(ws + 21495808);   // 64 steps x 512 blocks x 4KB = 134217728 B

  (void)hipFuncSetAttribute((const void*)k_gru0,
                            hipFuncAttributeMaxDynamicSharedMemorySize, A_LDS);
  (void)hipFuncSetAttribute((const void*)k_gru1,
                            hipFuncAttributeMaxDynamicSharedMemorySize, B_LDS);
  (void)hipFuncSetAttribute((const void*)k_out2,
                            hipFuncAttributeMaxDynamicSharedMemorySize, 84096);

  k_gru0<<<512, 512, A_LDS, stream>>>(x, wih0, whh0, bih0, bhh0, h0seq);
  k_gru1<<<512, 512, B_LDS, stream>>>(wih1, whh1, bih1, bhh1, h0seq, hraw);
  k_bn1p<<<128, 256, 0, stream>>>(hraw, bn2p);
  k_bn1r<<<1, 128, 0, stream>>>(bn2p, mu1, rs1);
  k_attp<<<128, 256, 0, stream>>>(hraw, mu1, rs1, g1, b1, hidden, mvec, gpart, mhpart);
  k_attfa<<<64, 256, 0, stream>>>(gpart, mhpart, gfull, mhfull);
  k_attfb<<<128, 128, 0, stream>>>(gfull, mhfull, fcw, m2, uvec);
  k_out2<<<256, 256, 84096, stream>>>(hidden, mvec, m2, uvec, fcb, out2, bn2p);
  k_bn2<<<1, 128, 0, stream>>>(bn2p, mu2, rs2);
  k_fin<<<2048, 256, 0, stream>>>(out2, mu2, rs2, g2, b2, fcow, fcob, (float*)d_out);
}

// Round 9
// 329.246 us; speedup vs baseline: 1.8989x; 1.0403x over previous
//
#include <hip/hip_runtime.h>

typedef unsigned short u16;
typedef short bf16x8 __attribute__((ext_vector_type(8)));
typedef float f32x4 __attribute__((ext_vector_type(4)));

#define NBATCH 8192

__device__ __forceinline__ f32x4 mfma16(bf16x8 a, bf16x8 b, f32x4 c) {
  return __builtin_amdgcn_mfma_f32_16x16x32_bf16(a, b, c, 0, 0, 0);
}
__device__ __forceinline__ u16 f2bf(float f) {
  unsigned int u = __float_as_uint(f);
  return (u16)((u + 0x7FFFu + ((u >> 16) & 1u)) >> 16);
}
__device__ __forceinline__ float bf2f(u16 h) {
  return __uint_as_float(((unsigned int)h) << 16);
}
__device__ __forceinline__ float sigm(float x) {
  return __builtin_amdgcn_rcpf(1.f + __builtin_amdgcn_exp2f(-1.44269504f * x));
}
__device__ __forceinline__ float tanh_(float x) {
  float t = __builtin_amdgcn_exp2f(2.88539008f * x);
  return 1.f - 2.f * __builtin_amdgcn_rcpf(t + 1.f);
}
__device__ __forceinline__ bf16x8 pack8(const float* p) {
  float4 a = *(const float4*)p, b = *(const float4*)(p + 4);
  bf16x8 r;
  r[0] = (short)f2bf(a.x); r[1] = (short)f2bf(a.y);
  r[2] = (short)f2bf(a.z); r[3] = (short)f2bf(a.w);
  r[4] = (short)f2bf(b.x); r[5] = (short)f2bf(b.y);
  r[6] = (short)f2bf(b.z); r[7] = (short)f2bf(b.w);
  return r;
}

// =====================================================================
// R8 post-mortem: spill-free but co-residency STILL failed at 76KB LDS
// (occupancy 22% = 1 block/CU), and half the per-step LDS instructions
// were re-reads of loop-invariant weights. R9: ALL weights in registers
// (k_gru0: 60 VGPR of weights, k_gru1: 96 -> totals ~85/~118 <= 128
// budget), LDS = recurrent state only (10KB / 16KB). This halves LDS
// instructions per step, removes weight-read bank conflicts, and makes
// 2-blocks/CU co-residency unambiguous regardless of which LDS
// mechanism blocked R8 (rounding or >64KB policy). 1 barrier/step in
// both kernels. Numerics bit-identical to R3-R8.
// =====================================================================

// ---------------- k_gru0: layer-0 recurrence ----------------
// LDS: h0b dbuf 2x4K | x dbuf 2x1K = 10K
#define A_H0B  0
#define A_XB   8192
#define A_LDS  10240

#define GRU0_STEP(RD, WR, T)                                                    \
  {                                                                             \
    if (xact && (T) < 63) {                                                     \
      u16 xh = f2bf(xv);                                                        \
      u16 xl = f2bf(xv - bf2f(xh));                                             \
      char* xw = sm + A_XB + (WR)*1024 + xm*64 + xd*2;                          \
      *(u16*)xw = xh; *(u16*)(xw + 16) = xl; *(u16*)(xw + 32) = xh;             \
      if ((T) < 62) xv = gx[(T) + 2];                                           \
    }                                                                           \
    f32x4 accr = {brzr, brzr, brzr, brzr};                                      \
    f32x4 accz = {brzz, brzz, brzz, brzz};                                      \
    f32x4 acch = {bhn0, bhn0, bhn0, bhn0};                                      \
    f32x4 acci = {bin0, bin0, bin0, bin0};                                      \
    _Pragma("unroll") for (int ki = 0; ki < 4; ++ki) {                          \
      bf16x8 a0 = *(bf16x8*)(sm + A_H0B + (RD)*4096 + arow0 + ad[ki]);          \
      accr = mfma16(a0, wr0[ki], accr);                                         \
      accz = mfma16(a0, wz0[ki], accz);                                         \
      acch = mfma16(a0, wn0[ki], acch);                                         \
    }                                                                           \
    {                                                                           \
      bf16x8 ax0 = *(bf16x8*)(sm + A_XB + (RD)*1024 + xr0);                     \
      accr = mfma16(ax0, wf0a, accr);                                           \
      accz = mfma16(ax0, wf0b, accz);                                           \
      acci = mfma16(ax0, wf0c, acci);                                           \
    }                                                                           \
    if ((T) >= 1) { /* stream h0(T-1) swizzled tile to global, verbatim */      \
      uint2 gv = *(const uint2*)(sm + A_H0B + (RD)*4096 + tid*8);               \
      *(uint2*)(h0seq + (size_t)((T)-1)*2097152 + gofs) = gv;                   \
    }                                                                           \
    _Pragma("unroll") for (int r = 0; r < 4; ++r) {                             \
      float rr = sigm(accr[r]);                                                 \
      float zz = sigm(accz[r]);                                                 \
      float nn = tanh_(__builtin_fmaf(rr, acch[r], acci[r]));                   \
      float h = h0s[r]; h = __builtin_fmaf(zz, h - nn, nn); h0s[r] = h;         \
      *(u16*)(sm + A_H0B + (WR)*4096 + st[r]) = f2bf(h);                        \
    }                                                                           \
    __syncthreads();                                                            \
  }

__global__ __attribute__((amdgpu_flat_work_group_size(512, 512)))
void k_gru0(const float* __restrict__ x,
            const float* __restrict__ wih0, const float* __restrict__ whh0,
            const float* __restrict__ bih0, const float* __restrict__ bhh0,
            char* __restrict__ h0seq) {
  extern __shared__ char sm[];
  const int tid = threadIdx.x;
  const int wid = tid >> 6;
  const int lane = tid & 63;
  const int lq = lane >> 4;
  const int ul = lane & 15;
  const int u  = wid * 16 + ul;
  const int n0 = blockIdx.x * 16;
  const int sx = (ul & 7) << 4;
  const int gofs = blockIdx.x * 4096 + tid * 8;

  // zero h0b dbuf + x dbuf (10240 B)
  for (int idx = tid; idx < 2560; idx += 512)
    *(float*)(sm + A_H0B + idx * 4) = 0.f;

  // ALL W_hh0 gate rows for unit u in registers (r, z, n)
  bf16x8 wr0[4], wz0[4], wn0[4];
#pragma unroll
  for (int ki = 0; ki < 4; ++ki) {
    wr0[ki] = pack8(whh0 + u * 128 + ki * 32 + lq * 8);
    wz0[ki] = pack8(whh0 + (128 + u) * 128 + ki * 32 + lq * 8);
    wn0[ki] = pack8(whh0 + (256 + u) * 128 + ki * 32 + lq * 8);
  }

  // W_ih0 hi/lo fragments (k0-5: whi for x-hi; k8-13: whi for x-lo; k16-21: wlo)
  bf16x8 wf0a, wf0b, wf0c;
  {
    u16 t0[8] = {0,0,0,0,0,0,0,0}, t1[8] = {0,0,0,0,0,0,0,0}, t2[8] = {0,0,0,0,0,0,0,0};
    u16* ts[3] = {t0, t1, t2};
#pragma unroll
    for (int i = 0; i < 3; ++i) {
      int g = u + 128 * i;
      if (lq < 2) {
        for (int d = 0; d < 6; ++d) ts[i][d] = f2bf(wih0[g * 6 + d]);
      } else if (lq == 2) {
        for (int d = 0; d < 6; ++d) {
          float w = wih0[g * 6 + d];
          u16 h = f2bf(w);
          ts[i][d] = f2bf(w - bf2f(h));
        }
      }
    }
    wf0a = *(bf16x8*)t0; wf0b = *(bf16x8*)t1; wf0c = *(bf16x8*)t2;
  }
  const float brzr = bih0[u] + bhh0[u];
  const float brzz = bih0[u + 128] + bhh0[u + 128];
  const float bin0 = bih0[u + 256], bhn0 = bhh0[u + 256];

  int ad[4];
#pragma unroll
  for (int ki = 0; ki < 4; ++ki) ad[ki] = (ki * 64 + lq * 16) ^ sx;
  const int arow0 = ul * 256;
  const int xr0 = ul * 64 + lq * 16;
  int st[4];
#pragma unroll
  for (int r = 0; r < 4; ++r) {
    int m = lq * 4 + r;
    st[r] = m * 256 + ((u * 2) ^ ((m & 7) << 4));
  }

  float h0s[4];
#pragma unroll
  for (int r = 0; r < 4; ++r) h0s[r] = 0.f;

  // x loaders: 96 threads own one (sample, feature) pair
  const int xm = tid / 6, xd = tid - 6 * xm;
  const bool xact = tid < 96;
  const float* gx = x + (size_t)(n0 + xm) * 384 + xd * 64;

  __syncthreads();  // zeros visible

  float xv = 0.f;
  if (xact) {
    float x0 = gx[0];
    u16 h = f2bf(x0);
    u16 l = f2bf(x0 - bf2f(h));
    char* p = sm + A_XB + xm * 64 + xd * 2;
    *(u16*)p = h; *(u16*)(p + 16) = l; *(u16*)(p + 32) = h;
    xv = gx[1];
  }
  __syncthreads();  // x(0) visible

  for (int t = 0; t < 64; t += 2) {
    GRU0_STEP(0, 1, t)
    GRU0_STEP(1, 0, t + 1)
  }
  // epilogue: h0(63) sits in buf0
  {
    uint2 gv = *(const uint2*)(sm + A_H0B + tid * 8);
    *(uint2*)(h0seq + (size_t)63 * 2097152 + gofs) = gv;
  }
}

// ---------------- k_gru1: layer-1 recurrence ----------------
// LDS: h0in dbuf 2x4K | h1b dbuf 2x4K = 16K. 1 barrier/step.
#define B_H0IN 0
#define B_H1B  8192
#define B_LDS  16384

#define GRU1_STEP(RD, WR, T)                                                    \
  {                                                                             \
    uint2 hv = {0u, 0u};                                                        \
    if ((T) < 63) hv = *(const uint2*)(gsrc + (size_t)((T)+1)*2097152);         \
    f32x4 accr = {brzr, brzr, brzr, brzr};                                      \
    f32x4 accz = {brzz, brzz, brzz, brzz};                                      \
    f32x4 acci = {bin1, bin1, bin1, bin1};                                      \
    f32x4 acch = {bhn1, bhn1, bhn1, bhn1};                                      \
    _Pragma("unroll") for (int ki = 0; ki < 4; ++ki) {                          \
      bf16x8 p0 = *(bf16x8*)(sm + B_H0IN + (RD)*4096 + arow0 + ad[ki]);         \
      bf16x8 q0 = *(bf16x8*)(sm + B_H1B + (RD)*4096 + arow0 + ad[ki]);          \
      accr = mfma16(p0, wih1f[0][ki], accr);                                    \
      accr = mfma16(q0, wr1[ki], accr);                                         \
      accz = mfma16(p0, wih1f[1][ki], accz);                                    \
      accz = mfma16(q0, wz1[ki], accz);                                         \
      acci = mfma16(p0, wih1f[2][ki], acci);                                    \
      acch = mfma16(q0, wn1[ki], acch);                                         \
    }                                                                           \
    if ((T) < 63) *(uint2*)(sm + B_H0IN + (WR)*4096 + tid*8) = hv;              \
    _Pragma("unroll") for (int r = 0; r < 4; ++r) {                             \
      float rr = sigm(accr[r]);                                                 \
      float zz = sigm(accz[r]);                                                 \
      float nn = tanh_(__builtin_fmaf(rr, acch[r], acci[r]));                   \
      float h = h1s[r]; h = __builtin_fmaf(zz, h - nn, nn); h1s[r] = h;         \
      *(u16*)(sm + B_H1B + (WR)*4096 + st[r]) = f2bf(h);                        \
    }                                                                           \
    __syncthreads();                                                            \
  }

__global__ __attribute__((amdgpu_flat_work_group_size(512, 512)))
void k_gru1(const float* __restrict__ wih1, const float* __restrict__ whh1,
            const float* __restrict__ bih1, const float* __restrict__ bhh1,
            const char* __restrict__ h0seq, float* __restrict__ hraw) {
  extern __shared__ char sm[];
  const int tid = threadIdx.x;
  const int wid = tid >> 6;
  const int lane = tid & 63;
  const int lq = lane >> 4;
  const int ul = lane & 15;
  const int u  = wid * 16 + ul;
  const int n0 = blockIdx.x * 16;
  const int sx = (ul & 7) << 4;
  const char* gsrc = h0seq + blockIdx.x * 4096 + tid * 8;

  // zero h1b buf0 (read at t=0)
  for (int idx = tid; idx < 1024; idx += 512)
    *(float*)(sm + B_H1B + idx * 4) = 0.f;
  // h0(0) into h0in buf0 (verbatim copy of k_gru0's swizzled tile)
  {
    uint2 h0v = *(const uint2*)(gsrc);
    *(uint2*)(sm + B_H0IN + tid * 8) = h0v;
  }
  // ALL weights in registers: W_ih1 rows {u,u+128,u+256}; W_hh1 rows {u,u+128,u+256}
  bf16x8 wih1f[3][4], wr1[4], wz1[4], wn1[4];
#pragma unroll
  for (int i = 0; i < 3; ++i) {
    int g = u + 128 * i;
#pragma unroll
    for (int ki = 0; ki < 4; ++ki)
      wih1f[i][ki] = pack8(wih1 + g * 128 + ki * 32 + lq * 8);
  }
#pragma unroll
  for (int ki = 0; ki < 4; ++ki) {
    wr1[ki] = pack8(whh1 + u * 128 + ki * 32 + lq * 8);
    wz1[ki] = pack8(whh1 + (128 + u) * 128 + ki * 32 + lq * 8);
    wn1[ki] = pack8(whh1 + (256 + u) * 128 + ki * 32 + lq * 8);
  }

  const float brzr = bih1[u] + bhh1[u];
  const float brzz = bih1[u + 128] + bhh1[u + 128];
  const float bin1 = bih1[u + 256], bhn1 = bhh1[u + 256];

  int ad[4];
#pragma unroll
  for (int ki = 0; ki < 4; ++ki) ad[ki] = (ki * 64 + lq * 16) ^ sx;
  const int arow0 = ul * 256;
  int st[4];
#pragma unroll
  for (int r = 0; r < 4; ++r) {
    int m = lq * 4 + r;
    st[r] = m * 256 + ((u * 2) ^ ((m & 7) << 4));
  }

  float h1s[4];
#pragma unroll
  for (int r = 0; r < 4; ++r) h1s[r] = 0.f;

  __syncthreads();  // staging visible

  for (int t = 0; t < 64; t += 2) {
    GRU1_STEP(0, 1, t)
    GRU1_STEP(1, 0, t + 1)
  }

#pragma unroll
  for (int r = 0; r < 4; ++r) {
    int m = lq * 4 + r;
    hraw[(size_t)(n0 + m) * 128 + u] = h1s[r];
  }
}

// ------------------------- BN1 partials (coalesced) -------------------------
__global__ void k_bn1p(const float* __restrict__ hraw, float* __restrict__ p) {
  __shared__ float s0[256], s1[256];
  int tid = threadIdx.x, b = blockIdx.x;
  int f = tid & 127, r = tid >> 7;
  float s = 0.f, q = 0.f;
  for (int n = b * 64 + r; n < b * 64 + 64; n += 2) {
    float v = hraw[(size_t)n * 128 + f];
    s += v; q += v * v;
  }
  s0[tid] = s; s1[tid] = q;
  __syncthreads();
  if (tid < 128) {
    p[b * 256 + tid] = s0[tid] + s0[tid + 128];
    p[b * 256 + 128 + tid] = s1[tid] + s1[tid + 128];
  }
}

__global__ void k_bn1r(const float* __restrict__ p, float* __restrict__ mu1,
                       float* __restrict__ rs1) {
  int f = threadIdx.x;
  float s = 0.f, q = 0.f;
  for (int b = 0; b < 128; ++b) { s += p[b * 256 + f]; q += p[b * 256 + 128 + f]; }
  float mu = s / 8192.f, var = q / 8192.f - mu * mu;
  mu1[f] = mu; rs1[f] = rsqrtf(var + 1e-5f);
}

// ------------------------- BN1 apply + row means + Gram/mh partials -------------------------
__global__ void k_attp(const float* __restrict__ hraw, const float* __restrict__ mu1,
                       const float* __restrict__ rs1, const float* __restrict__ g1,
                       const float* __restrict__ b1, float* __restrict__ hidden,
                       float* __restrict__ mvec, float* __restrict__ gpart,
                       float* __restrict__ mhpart) {
  __shared__ float hid[64][128];
  __shared__ float mld[64];
  int tid = threadIdx.x, blk = blockIdx.x, n0 = blk * 64;
  for (int idx = tid; idx < 64 * 128; idx += 256) {
    int n = idx >> 7, f = idx & 127;
    float v = (hraw[(size_t)(n0 + n) * 128 + f] - mu1[f]) * rs1[f] * g1[f] + b1[f];
    hid[n][f] = v;
    hidden[(size_t)(n0 + n) * 128 + f] = v;
  }
  __syncthreads();
  if (tid < 64) {
    float s = 0.f;
    for (int f = 0; f < 128; ++f) s += hid[tid][f];
    s *= (1.f / 128.f);
    mld[tid] = s; mvec[n0 + tid] = s;
  }
  __syncthreads();
  int i = tid >> 1, j0 = (tid & 1) * 64;
  float acc[64];
#pragma unroll
  for (int j = 0; j < 64; ++j) acc[j] = 0.f;
  for (int n = 0; n < 64; ++n) {
    float a = hid[n][i];
#pragma unroll
    for (int j = 0; j < 64; ++j) acc[j] += a * hid[n][j0 + j];
  }
#pragma unroll
  for (int j = 0; j < 64; ++j) gpart[(size_t)blk * 16384 + i * 128 + j0 + j] = acc[j];
  if (tid < 128) {
    float s = 0.f;
    for (int n = 0; n < 64; ++n) s += mld[n] * hid[n][tid];
    mhpart[blk * 128 + tid] = s;
  }
}

// ------------------------- reduce Gram/mh partials -------------------------
__global__ void k_attfa(const float* __restrict__ gpart, const float* __restrict__ mhpart,
                        float* __restrict__ gfull, float* __restrict__ mhfull) {
  int idx = blockIdx.x * 256 + threadIdx.x;
  float s = 0.f;
  for (int b = 0; b < 128; ++b) s += gpart[(size_t)b * 16384 + idx];
  gfull[idx] = s;
  if (blockIdx.x == 0 && threadIdx.x < 128) {
    float t = 0.f;
    for (int b = 0; b < 128; ++b) t += mhpart[b * 128 + threadIdx.x];
    mhfull[threadIdx.x] = t;
  }
}

// ------------------------- M2 = (G/H) @ fc_w^T ; u = mh @ fc_w^T -------------------------
__global__ void k_attfb(const float* __restrict__ gfull, const float* __restrict__ mhfull,
                        const float* __restrict__ fcw, float* __restrict__ m2,
                        float* __restrict__ uvec) {
  int idx = blockIdx.x * 128 + threadIdx.x;
  int k = idx >> 7, j = idx & 127;
  const float4* ga = (const float4*)(gfull + k * 128);
  const float4* fb = (const float4*)(fcw + j * 128);
  float a0 = 0.f, a1 = 0.f, a2 = 0.f, a3 = 0.f;
#pragma unroll 8
  for (int f = 0; f < 32; ++f) {
    float4 a = ga[f], b = fb[f];
    a0 += a.x * b.x; a1 += a.y * b.y; a2 += a.z * b.z; a3 += a.w * b.w;
  }
  m2[idx] = (a0 + a1 + a2 + a3) * (1.f / 128.f);
  if (idx < 128) {
    float s = 0.f;
    const float* fr = fcw + idx * 128;
#pragma unroll 8
    for (int f = 0; f < 128; ++f) s += mhfull[f] * fr[f];
    uvec[idx] = s;
  }
}

// ------------------------- out2 = hidden@M2 - m*u + fc_b ; BN2 partials -------------------------
__global__ void k_out2(const float* __restrict__ hidden, const float* __restrict__ mvec,
                       const float* __restrict__ m2g, const float* __restrict__ uvec,
                       const float* __restrict__ fcb, float* __restrict__ out2,
                       float* __restrict__ bn2p) {
  extern __shared__ char smo[];
  float* m2l = (float*)smo;
  float* hl = m2l + 16384;
  float* ml = hl + 4096;
  float* red = ml + 32;
  int tid = threadIdx.x, blk = blockIdx.x, n0 = blk * 32;
  for (int idx = tid; idx < 16384; idx += 256) m2l[idx] = m2g[idx];
  for (int idx = tid; idx < 4096; idx += 256) hl[idx] = hidden[(size_t)n0 * 128 + idx];
  if (tid < 32) ml[tid] = mvec[n0 + tid];
  __syncthreads();
  int j = tid & 127, rg = tid >> 7;
  float uj = uvec[j], bj = fcb[j];
  float s1 = 0.f, s2 = 0.f;
  for (int q = 0; q < 16; ++q) {
    int nl = rg * 16 + q;
    float s = bj - ml[nl] * uj;
    const float* hr = hl + nl * 128;
#pragma unroll 8
    for (int k = 0; k < 128; ++k) s += hr[k] * m2l[k * 128 + j];
    out2[(size_t)(n0 + nl) * 128 + j] = s;
    s1 += s; s2 += s * s;
  }
  red[tid] = s1; red[256 + tid] = s2;
  __syncthreads();
  if (tid < 128) {
    bn2p[blk * 256 + tid] = red[tid] + red[128 + tid];
    bn2p[blk * 256 + 128 + tid] = red[256 + tid] + red[384 + tid];
  }
}

// ------------------------- BN2 stats -------------------------
__global__ void k_bn2(const float* __restrict__ bn2p, float* __restrict__ mu2,
                      float* __restrict__ rs2) {
  int j = threadIdx.x;
  float s = 0.f, q = 0.f;
  for (int b = 0; b < 256; ++b) {
    s += bn2p[b * 256 + j];
    q += bn2p[b * 256 + 128 + j];
  }
  float mu = s / 8192.f, var = q / 8192.f - mu * mu;
  mu2[j] = mu; rs2[j] = rsqrtf(var + 1e-5f);
}

// ------------------------- BN2 apply + leaky-relu + final GEMV -------------------------
__global__ void k_fin(const float* __restrict__ out2, const float* __restrict__ mu2,
                      const float* __restrict__ rs2, const float* __restrict__ g2,
                      const float* __restrict__ b2, const float* __restrict__ fcow,
                      const float* __restrict__ fcob, float* __restrict__ y) {
  int tid = threadIdx.x, lane = tid & 63, w = tid >> 6;
  int n = blockIdx.x * 4 + w;
  float s = 0.f;
#pragma unroll
  for (int h = 0; h < 2; ++h) {
    int j = lane + h * 64;
    float v = (out2[(size_t)n * 128 + j] - mu2[j]) * rs2[j] * g2[j] + b2[j];
    v = fmaxf(v, 0.01f * v);
    s += v * fcow[j];
  }
  for (int off = 32; off; off >>= 1) s += __shfl_down(s, off);
  if (!lane) y[n] = s + fcob[0];
}

// ------------------------- launch -------------------------
extern "C" void kernel_launch(void* const* d_in, const int* in_sizes, int n_in,
                              void* d_out, int out_size, void* d_ws, size_t ws_size,
                              hipStream_t stream) {
  const float* x    = (const float*)d_in[0];
  const float* wih0 = (const float*)d_in[1];
  const float* whh0 = (const float*)d_in[2];
  const float* bih0 = (const float*)d_in[3];
  const float* bhh0 = (const float*)d_in[4];
  const float* wih1 = (const float*)d_in[5];
  const float* whh1 = (const float*)d_in[6];
  const float* bih1 = (const float*)d_in[7];
  const float* bhh1 = (const float*)d_in[8];
  const float* g1   = (const float*)d_in[9];
  const float* b1   = (const float*)d_in[10];
  const float* fcw  = (const float*)d_in[11];
  const float* fcb  = (const float*)d_in[12];
  const float* g2   = (const float*)d_in[13];
  const float* b2   = (const float*)d_in[14];
  const float* fcow = (const float*)d_in[15];
  const float* fcob = (const float*)d_in[16];

  char* ws = (char*)d_ws;
  float* hraw   = (float*)(ws + 0);
  float* hidden = (float*)(ws + 4194304);
  float* mvec   = (float*)(ws + 8388608);
  float* mu1    = (float*)(ws + 8421376);
  float* rs1    = (float*)(ws + 8421888);
  float* gpart  = (float*)(ws + 8422400);
  float* mhpart = (float*)(ws + 16811008);
  float* m2     = (float*)(ws + 16876544);
  float* uvec   = (float*)(ws + 16942080);
  float* out2   = (float*)(ws + 16942592);
  float* bn2p   = (float*)(ws + 21136896);  // reused: bn1 partials live here first
  float* mu2    = (float*)(ws + 21399040);
  float* rs2    = (float*)(ws + 21399552);
  float* gfull  = (float*)(ws + 21400064);
  float* mhfull = (float*)(ws + 21465600);
  char*  h0seq  = (char*)(ws + 21495808);   // 64 steps x 512 blocks x 4KB = 134217728 B

  (void)hipFuncSetAttribute((const void*)k_out2,
                            hipFuncAttributeMaxDynamicSharedMemorySize, 84096);

  k_gru0<<<512, 512, A_LDS, stream>>>(x, wih0, whh0, bih0, bhh0, h0seq);
  k_gru1<<<512, 512, B_LDS, stream>>>(wih1, whh1, bih1, bhh1, h0seq, hraw);
  k_bn1p<<<128, 256, 0, stream>>>(hraw, bn2p);
  k_bn1r<<<1, 128, 0, stream>>>(bn2p, mu1, rs1);
  k_attp<<<128, 256, 0, stream>>>(hraw, mu1, rs1, g1, b1, hidden, mvec, gpart, mhpart);
  k_attfa<<<64, 256, 0, stream>>>(gpart, mhpart, gfull, mhfull);
  k_attfb<<<128, 128, 0, stream>>>(gfull, mhfull, fcw, m2, uvec);
  k_out2<<<256, 256, 84096, stream>>>(hidden, mvec, m2, uvec, fcb, out2, bn2p);
  k_bn2<<<1, 128, 0, stream>>>(bn2p, mu2, rs2);
  k_fin<<<2048, 256, 0, stream>>>(out2, mu2, rs2, g2, b2, fcow, fcob, (float*)d_out);
}